// Round 1
// baseline (770.460 us; speedup 1.0000x reference)
//
#include <hip/hip_runtime.h>
#include <math.h>

typedef float vf4 __attribute__((ext_vector_type(4)));

#define CODE_SIZE 1024
#define CODE_DIM  256
#define BB        64
#define HWSZ      1024                       // H*W = 32*32
#define NROWS     (BB * HWSZ)                // 65536
#define QELEMS    (BB * CODE_DIM * HWSZ)     // 16777216

// ---------------------------------------------------------------------------
// sw[code] = numpy-pairwise sum of fl(w*w) over 256 contiguous elements.
// ---------------------------------------------------------------------------
__global__ void k_sumsq_w(const float* __restrict__ w, float* __restrict__ sw) {
#pragma clang fp contract(off)
  const int code = blockIdx.x * blockDim.x + threadIdx.x;
  if (code >= CODE_SIZE) return;
  const float* row = w + (size_t)code * CODE_DIM;
  float halves[2];
  for (int h = 0; h < 2; ++h) {
    const float* p = row + h * 128;
    float r[8];
#pragma unroll
    for (int j = 0; j < 8; ++j) { float v = p[j]; r[j] = v * v; }
    for (int i = 8; i < 128; i += 8) {
#pragma unroll
      for (int j = 0; j < 8; ++j) { float v = p[i + j]; r[j] += v * v; }
    }
    halves[h] = ((r[0] + r[1]) + (r[2] + r[3])) + ((r[4] + r[5]) + (r[6] + r[7]));
  }
  sw[code] = halves[0] + halves[1];
}

// sx[n] = same pairwise over fl(x*x), x strided by HWSZ along channel dim.
__global__ void k_sumsq_x(const float* __restrict__ x, float* __restrict__ sx) {
#pragma clang fp contract(off)
  const int n = blockIdx.x * blockDim.x + threadIdx.x;   // 0..65535
  const int b = n >> 10, hw = n & 1023;
  const float* p = x + (size_t)b * CODE_DIM * HWSZ + hw;
  float halves[2];
  for (int h = 0; h < 2; ++h) {
    const float* q = p + (size_t)(h * 128) * HWSZ;
    float r[8];
#pragma unroll
    for (int j = 0; j < 8; ++j) { float v = q[(size_t)j * HWSZ]; r[j] = v * v; }
    for (int i = 8; i < 128; i += 8) {
#pragma unroll
      for (int j = 0; j < 8; ++j) { float v = q[(size_t)(i + j) * HWSZ]; r[j] += v * v; }
    }
    halves[h] = ((r[0] + r[1]) + (r[2] + r[3])) + ((r[4] + r[5]) + (r[6] + r[7]));
  }
  sx[n] = halves[0] + halves[1];
}

// ---------------------------------------------------------------------------
// GEMM-argmin. Block = 64 rows x 256-code chunks (4 chunks), KC=32.
// Thread tile 8x8 -> 64 FMA per 4 ds_read_b128; both LDS reads are 8-way
// same-address broadcasts (conflict-free).
// NEW (this round): register double-buffer of the staged fragments.
// Old structure stalled 32% of cycles (VALUBusy 68%) because the global
// load -> LDS write sat INSIDE the barrier pair (vmcnt wait with only 4
// blocks/CU to cover ~200-900cy latency). Now: loads for step kc+1 are
// issued right after the second barrier and consumed by a pure reg->LDS
// write phase next iteration; the 2048-FMA compute phase (~4096 cyc/wave)
// hides the latency.
// Accumulator: single sequential fmaf chain over k=0..255 (chunk-outer,
// kc-inner) — bitwise-matching np's sgemm. Key = fl(fl(sx-2G)+sw), contract
// off. Tie-break lowest index everywhere (ascending scan + strict <).
// LDS: xs 8KB + ws 32KB = 40960 B -> 4 blocks/CU.
// VGPR: acc 64 + prefetch 40 (+temps) — targets the 128 cap of (256,4).
// ---------------------------------------------------------------------------
#define MT  64
#define NTC 256
#define NCH (CODE_SIZE / NTC)
#define KC  32

__launch_bounds__(256, 4)
__global__ void k_argmin(const float* __restrict__ x, const float* __restrict__ w,
                         const float* __restrict__ sx, const float* __restrict__ sw,
                         float* __restrict__ oidx) {
  __shared__ float xs[KC * MT];    // [k][r], 8 KB
  __shared__ float ws[KC * NTC];   // [k][code], 32 KB; overlaid by reduction

  const int t   = threadIdx.x;
  const int n0  = blockIdx.x * MT;
  const int b   = n0 >> 10;
  const int hw0 = n0 & 1023;
  const int rt  = t & 7;     // rows rt*8 .. rt*8+7
  const int ct  = t >> 3;    // code-group 0..31: codes ct*8..ct*8+7 per chunk

  float bk[8]; float bi[8];
#pragma unroll
  for (int ri = 0; ri < 8; ++ri) { bk[ri] = INFINITY; bi[ri] = (float)CODE_SIZE; }

  // ---- prefetch registers (double-buffer vs LDS) ----
  vf4 pxv[2];
  vf4 pwv[8];

  // issue global loads for step (chunk, kc) into pxv/pwv
  auto issue_prefetch = [&](int chunk, int kc) {
    const int kbase = kc * KC;
#pragma unroll
    for (int i = 0; i < 2; ++i) {
      const int j  = t + 256 * i;
      const int k  = j >> 4;      // 0..31
      const int rq = j & 15;      // row quad
      pxv[i] = *(const vf4*)(x + ((size_t)(b * CODE_DIM + kbase + k) * HWSZ + hw0 + rq * 4));
    }
    const float* wr = w + (size_t)(chunk * NTC + t) * CODE_DIM + kbase;
#pragma unroll
    for (int q = 0; q < 8; ++q) pwv[q] = *(const vf4*)(wr + q * 4);
  };

  issue_prefetch(0, 0);

  for (int chunk = 0; chunk < NCH; ++chunk) {
    const int code0 = chunk * NTC;

    float acc[8][8];
#pragma unroll
    for (int ri = 0; ri < 8; ++ri)
#pragma unroll
      for (int cj = 0; cj < 8; ++cj) acc[ri][cj] = 0.0f;

    for (int kc = 0; kc < CODE_DIM / KC; ++kc) {
      __syncthreads();   // previous stage's readers done with xs/ws
      // write phase: pure reg -> LDS (prefetched last iteration)
#pragma unroll
      for (int i = 0; i < 2; ++i) {
        const int j  = t + 256 * i;
        const int k  = j >> 4;
        const int rq = j & 15;
        *(vf4*)(xs + k * MT + rq * 4) = pxv[i];
      }
      // ws[k][code]: thread t owns code code0+t; LDS writes bank = t mod 32,
      // lanes t and t+32 alias -> 2-way, free
#pragma unroll
      for (int q = 0; q < 8; ++q) {
        ws[(q * 4 + 0) * NTC + t] = pwv[q].x;
        ws[(q * 4 + 1) * NTC + t] = pwv[q].y;
        ws[(q * 4 + 2) * NTC + t] = pwv[q].z;
        ws[(q * 4 + 3) * NTC + t] = pwv[q].w;
      }
      __syncthreads();

      // issue loads for the NEXT step; latency hides under the FMA phase.
      // Tail wraps to (0,0) — harmless valid loads.
      {
        int nkc = kc + 1, nch = chunk;
        if (nkc == CODE_DIM / KC) { nkc = 0; nch = (chunk + 1 == NCH) ? 0 : chunk + 1; }
        issue_prefetch(nch, nkc);
      }

      const float* xp = xs + rt * 8;
      const float* wp = ws + ct * 8;
#pragma unroll 4
      for (int k = 0; k < KC; ++k) {
        vf4 xv0 = *(const vf4*)(xp + k * MT);
        vf4 xv1 = *(const vf4*)(xp + k * MT + 4);
        vf4 wv0 = *(const vf4*)(wp + k * NTC);
        vf4 wv1 = *(const vf4*)(wp + k * NTC + 4);
        float xr[8] = {xv0.x, xv0.y, xv0.z, xv0.w, xv1.x, xv1.y, xv1.z, xv1.w};
        float wc[8] = {wv0.x, wv0.y, wv0.z, wv0.w, wv1.x, wv1.y, wv1.z, wv1.w};
#pragma unroll
        for (int ri = 0; ri < 8; ++ri)
#pragma unroll
          for (int cj = 0; cj < 8; ++cj)
            acc[ri][cj] = fmaf(xr[ri], wc[cj], acc[ri][cj]);
      }
    }

    // per-chunk min-merge (codes ascending -> lowest-index tie-break)
    {
#pragma clang fp contract(off)
      float sxr[8];
#pragma unroll
      for (int ri = 0; ri < 8; ++ri) sxr[ri] = sx[n0 + rt * 8 + ri];
#pragma unroll
      for (int cj = 0; cj < 8; ++cj) {
        const int code = code0 + ct * 8 + cj;
        const float swv = sw[code];
        const float codef = (float)code;
#pragma unroll
        for (int ri = 0; ri < 8; ++ri) {
          const float tmp = sxr[ri] - 2.0f * acc[ri][cj];  // fl(sx - 2G)
          const float key = tmp + swv;                     // fl(.. + sw)
          if (key < bk[ri] || (key == bk[ri] && codef < bi[ri])) {
            bk[ri] = key; bi[ri] = codef;
          }
        }
      }
    }
  }

  // cross-thread reduction: 32 code-group slabs per row, overlaid on ws
  __syncthreads();
  float* redk = ws;                    // 32*64 floats
  float* redi = ws + 32 * MT;          // 32*64 floats (codes as float, exact)
#pragma unroll
  for (int ri = 0; ri < 8; ++ri) {
    const int row = rt * 8 + ri;
    redk[ct * MT + row] = bk[ri];
    redi[ct * MT + row] = bi[ri];
  }
  __syncthreads();
  if (t < MT) {
    float k0 = redk[t]; float i0 = redi[t];
    for (int q = 1; q < 32; ++q) {     // ascending ct -> ascending codes
      const float kq = redk[q * MT + t];
      const float iq = redi[q * MT + t];
      if (kq < k0 || (kq == k0 && iq < i0)) { k0 = kq; i0 = iq; }
    }
    oidx[n0 + t] = i0;   // idx output region read back as fp32
  }
}

// ---------------------------------------------------------------------------
// Epilogue: block = (b, 64-hw tile). Stage the 64 gathered w-rows into LDS
// (wt[c][r], stride 65 -> 2-way banks, free), then fully-coalesced vf4
// global reads/writes for q and ste = fl(fl(q - x) + x).
// ---------------------------------------------------------------------------
#define WT_S 65

__global__ void k_epilogue(const float* __restrict__ x, const float* __restrict__ w,
                           const float* __restrict__ oidx, float* __restrict__ out) {
#pragma clang fp contract(off)
  __shared__ int   idxs[MT];
  __shared__ float wt[CODE_DIM * WT_S];   // wt[c][r], 66560 B

  const int t   = threadIdx.x;
  const int n0  = blockIdx.x * MT;
  const int b   = n0 >> 10;
  const int hw0 = n0 & 1023;

  if (t < MT) idxs[t] = (int)oidx[n0 + t];
  __syncthreads();

  // stage wt: jobs j -> (r = j&63, cq = j>>6); lanes span r -> per-lane 16-B
  // gathers from 64 w-rows (L1/L2 absorb; each row consumed fully by the
  // 4 sibling threads), LDS writes bank=(c+r)%32 with r spanning -> free.
#pragma unroll
  for (int i = 0; i < 16; ++i) {
    const int j  = t + 256 * i;
    const int r  = j & 63;
    const int cq = j >> 6;     // 0..63
    vf4 v = *(const vf4*)(w + (size_t)idxs[r] * CODE_DIM + cq * 4);
    wt[(cq * 4 + 0) * WT_S + r] = v.x;
    wt[(cq * 4 + 1) * WT_S + r] = v.y;
    wt[(cq * 4 + 2) * WT_S + r] = v.z;
    wt[(cq * 4 + 3) * WT_S + r] = v.w;
  }
  __syncthreads();

  // outputs: jobs j -> (c = j>>4, rq = j&15); global vf4 fully coalesced
#pragma unroll
  for (int i = 0; i < 16; ++i) {
    const int j  = t + 256 * i;
    const int c  = j >> 4;     // 0..255
    const int rq = j & 15;
    const size_t off = (size_t)(b * CODE_DIM + c) * HWSZ + hw0 + rq * 4;
    vf4 xv = *(const vf4*)(x + off);
    vf4 q, s;
#pragma unroll
    for (int u = 0; u < 4; ++u) {
      const float qv = wt[c * WT_S + rq * 4 + u];
      q[u] = qv;
      const float d = qv - xv[u];
      s[u] = d + xv[u];
    }
    *(vf4*)(out + off) = q;
    *(vf4*)(out + (size_t)QELEMS + off) = s;
  }
}

extern "C" void kernel_launch(void* const* d_in, const int* in_sizes, int n_in,
                              void* d_out, int out_size, void* d_ws, size_t ws_size,
                              hipStream_t stream) {
  const float* x = (const float*)d_in[0];   // (64,256,32,32) fp32
  const float* w = (const float*)d_in[1];   // (1024,256) fp32
  float* out  = (float*)d_out;
  float* oidx = out + 2 * (size_t)QELEMS;          // idx region (written as float)
  // scratch for sx/sw lives inside the ste region; epilogue (which runs after
  // k_argmin completes, stream-ordered) overwrites it later
  float* sx = out + (size_t)QELEMS;                // 65536 floats
  float* sw = out + (size_t)QELEMS + NROWS;        // 1024 floats

  k_sumsq_w<<<CODE_SIZE / 256, 256, 0, stream>>>(w, sw);
  k_sumsq_x<<<NROWS / 256, 256, 0, stream>>>(x, sx);
  k_argmin<<<NROWS / MT, 256, 0, stream>>>(x, w, sx, sw, oidx);
  k_epilogue<<<NROWS / MT, 256, 0, stream>>>(x, w, oidx, out);
}

// Round 2
// 602.245 us; speedup vs baseline: 1.2793x; 1.2793x over previous
//
#include <hip/hip_runtime.h>
#include <math.h>

typedef float vf4 __attribute__((ext_vector_type(4)));

#define CODE_SIZE 1024
#define CODE_DIM  256
#define BB        64
#define HWSZ      1024                       // H*W = 32*32
#define NROWS     (BB * HWSZ)                // 65536
#define QELEMS    (BB * CODE_DIM * HWSZ)     // 16777216

// ---------------------------------------------------------------------------
// sw[code] = numpy-pairwise sum of fl(w*w) over 256 contiguous elements.
// ---------------------------------------------------------------------------
__global__ void k_sumsq_w(const float* __restrict__ w, float* __restrict__ sw) {
#pragma clang fp contract(off)
  const int code = blockIdx.x * blockDim.x + threadIdx.x;
  if (code >= CODE_SIZE) return;
  const float* row = w + (size_t)code * CODE_DIM;
  float halves[2];
  for (int h = 0; h < 2; ++h) {
    const float* p = row + h * 128;
    float r[8];
#pragma unroll
    for (int j = 0; j < 8; ++j) { float v = p[j]; r[j] = v * v; }
    for (int i = 8; i < 128; i += 8) {
#pragma unroll
      for (int j = 0; j < 8; ++j) { float v = p[i + j]; r[j] += v * v; }
    }
    halves[h] = ((r[0] + r[1]) + (r[2] + r[3])) + ((r[4] + r[5]) + (r[6] + r[7]));
  }
  sw[code] = halves[0] + halves[1];
}

// sx[n] = same pairwise over fl(x*x), x strided by HWSZ along channel dim.
__global__ void k_sumsq_x(const float* __restrict__ x, float* __restrict__ sx) {
#pragma clang fp contract(off)
  const int n = blockIdx.x * blockDim.x + threadIdx.x;   // 0..65535
  const int b = n >> 10, hw = n & 1023;
  const float* p = x + (size_t)b * CODE_DIM * HWSZ + hw;
  float halves[2];
  for (int h = 0; h < 2; ++h) {
    const float* q = p + (size_t)(h * 128) * HWSZ;
    float r[8];
#pragma unroll
    for (int j = 0; j < 8; ++j) { float v = q[(size_t)j * HWSZ]; r[j] = v * v; }
    for (int i = 8; i < 128; i += 8) {
#pragma unroll
      for (int j = 0; j < 8; ++j) { float v = q[(size_t)(i + j) * HWSZ]; r[j] += v * v; }
    }
    halves[h] = ((r[0] + r[1]) + (r[2] + r[3])) + ((r[4] + r[5]) + (r[6] + r[7]));
  }
  sx[n] = halves[0] + halves[1];
}

// ---------------------------------------------------------------------------
// GEMM-argmin. Block = 64 rows x 256-code chunks (4 chunks), KC=32.
// Thread tile 8x8 -> 64 FMA per 4 ds_read_b128; both LDS reads are 8-way
// same-address broadcasts (conflict-free).
// Register double-buffer of the staged fragments: loads for step kc+1 are
// issued right after the second barrier, consumed by a pure reg->LDS write
// phase next iteration; the 2048-FMA compute phase (~4096 cyc/wave) hides
// the global latency.
// ROUND-2 FIX: round 1 ran this structure under __launch_bounds__(256,4)
// (128-VGPR cap); the ~140-reg working set (acc 64 + prefetch 40 + FMA
// temps + addressing) SPILLED to scratch — WRITE_SIZE 2.3 MB -> 547 MB,
// VALUBusy 68 -> 50%, 444 -> 594 us. Now (256,3): ~168-VGPR cap, no spill,
// 3 blocks/CU (12 waves). Prefetch makes the barrier window short (~34 LDS
// writes), so 3 blocks suffice to cover it.
// Accumulator: single sequential fmaf chain over k=0..255 (chunk-outer,
// kc-inner) — bitwise-matching np's sgemm. Key = fl(fl(sx-2G)+sw), contract
// off. Tie-break lowest index everywhere (ascending scan + strict <).
// LDS: xs 8KB + ws 32KB = 40960 B (not the occupancy limiter at 3 blocks).
// ---------------------------------------------------------------------------
#define MT  64
#define NTC 256
#define NCH (CODE_SIZE / NTC)
#define KC  32

__launch_bounds__(256, 3)
__global__ void k_argmin(const float* __restrict__ x, const float* __restrict__ w,
                         const float* __restrict__ sx, const float* __restrict__ sw,
                         float* __restrict__ oidx) {
  __shared__ float xs[KC * MT];    // [k][r], 8 KB
  __shared__ float ws[KC * NTC];   // [k][code], 32 KB; overlaid by reduction

  const int t   = threadIdx.x;
  const int n0  = blockIdx.x * MT;
  const int b   = n0 >> 10;
  const int hw0 = n0 & 1023;
  const int rt  = t & 7;     // rows rt*8 .. rt*8+7
  const int ct  = t >> 3;    // code-group 0..31: codes ct*8..ct*8+7 per chunk

  float bk[8]; float bi[8];
#pragma unroll
  for (int ri = 0; ri < 8; ++ri) { bk[ri] = INFINITY; bi[ri] = (float)CODE_SIZE; }

  // ---- prefetch registers (double-buffer vs LDS) ----
  vf4 pxv[2];
  vf4 pwv[8];

  // issue global loads for step (chunk, kc) into pxv/pwv
  auto issue_prefetch = [&](int chunk, int kc) {
    const int kbase = kc * KC;
#pragma unroll
    for (int i = 0; i < 2; ++i) {
      const int j  = t + 256 * i;
      const int k  = j >> 4;      // 0..31
      const int rq = j & 15;      // row quad
      pxv[i] = *(const vf4*)(x + ((size_t)(b * CODE_DIM + kbase + k) * HWSZ + hw0 + rq * 4));
    }
    const float* wr = w + (size_t)(chunk * NTC + t) * CODE_DIM + kbase;
#pragma unroll
    for (int q = 0; q < 8; ++q) pwv[q] = *(const vf4*)(wr + q * 4);
  };

  issue_prefetch(0, 0);

  for (int chunk = 0; chunk < NCH; ++chunk) {
    const int code0 = chunk * NTC;

    float acc[8][8];
#pragma unroll
    for (int ri = 0; ri < 8; ++ri)
#pragma unroll
      for (int cj = 0; cj < 8; ++cj) acc[ri][cj] = 0.0f;

    for (int kc = 0; kc < CODE_DIM / KC; ++kc) {
      __syncthreads();   // previous stage's readers done with xs/ws
      // write phase: pure reg -> LDS (prefetched last iteration)
#pragma unroll
      for (int i = 0; i < 2; ++i) {
        const int j  = t + 256 * i;
        const int k  = j >> 4;
        const int rq = j & 15;
        *(vf4*)(xs + k * MT + rq * 4) = pxv[i];
      }
      // ws[k][code]: thread t owns code code0+t; LDS writes bank = t mod 32,
      // lanes t and t+32 alias -> 2-way, free
#pragma unroll
      for (int q = 0; q < 8; ++q) {
        ws[(q * 4 + 0) * NTC + t] = pwv[q].x;
        ws[(q * 4 + 1) * NTC + t] = pwv[q].y;
        ws[(q * 4 + 2) * NTC + t] = pwv[q].z;
        ws[(q * 4 + 3) * NTC + t] = pwv[q].w;
      }
      __syncthreads();

      // issue loads for the NEXT step; latency hides under the FMA phase.
      // Tail wraps to (0,0) — harmless valid loads.
      {
        int nkc = kc + 1, nch = chunk;
        if (nkc == CODE_DIM / KC) { nkc = 0; nch = (chunk + 1 == NCH) ? 0 : chunk + 1; }
        issue_prefetch(nch, nkc);
      }

      const float* xp = xs + rt * 8;
      const float* wp = ws + ct * 8;
#pragma unroll 4
      for (int k = 0; k < KC; ++k) {
        vf4 xv0 = *(const vf4*)(xp + k * MT);
        vf4 xv1 = *(const vf4*)(xp + k * MT + 4);
        vf4 wv0 = *(const vf4*)(wp + k * NTC);
        vf4 wv1 = *(const vf4*)(wp + k * NTC + 4);
        float xr[8] = {xv0.x, xv0.y, xv0.z, xv0.w, xv1.x, xv1.y, xv1.z, xv1.w};
        float wc[8] = {wv0.x, wv0.y, wv0.z, wv0.w, wv1.x, wv1.y, wv1.z, wv1.w};
#pragma unroll
        for (int ri = 0; ri < 8; ++ri)
#pragma unroll
          for (int cj = 0; cj < 8; ++cj)
            acc[ri][cj] = fmaf(xr[ri], wc[cj], acc[ri][cj]);
      }
    }

    // per-chunk min-merge (codes ascending -> lowest-index tie-break)
    {
#pragma clang fp contract(off)
      float sxr[8];
#pragma unroll
      for (int ri = 0; ri < 8; ++ri) sxr[ri] = sx[n0 + rt * 8 + ri];
#pragma unroll
      for (int cj = 0; cj < 8; ++cj) {
        const int code = code0 + ct * 8 + cj;
        const float swv = sw[code];
        const float codef = (float)code;
#pragma unroll
        for (int ri = 0; ri < 8; ++ri) {
          const float tmp = sxr[ri] - 2.0f * acc[ri][cj];  // fl(sx - 2G)
          const float key = tmp + swv;                     // fl(.. + sw)
          if (key < bk[ri] || (key == bk[ri] && codef < bi[ri])) {
            bk[ri] = key; bi[ri] = codef;
          }
        }
      }
    }
  }

  // cross-thread reduction: 32 code-group slabs per row, overlaid on ws
  __syncthreads();
  float* redk = ws;                    // 32*64 floats
  float* redi = ws + 32 * MT;          // 32*64 floats (codes as float, exact)
#pragma unroll
  for (int ri = 0; ri < 8; ++ri) {
    const int row = rt * 8 + ri;
    redk[ct * MT + row] = bk[ri];
    redi[ct * MT + row] = bi[ri];
  }
  __syncthreads();
  if (t < MT) {
    float k0 = redk[t]; float i0 = redi[t];
    for (int q = 1; q < 32; ++q) {     // ascending ct -> ascending codes
      const float kq = redk[q * MT + t];
      const float iq = redi[q * MT + t];
      if (kq < k0 || (kq == k0 && iq < i0)) { k0 = kq; i0 = iq; }
    }
    oidx[n0 + t] = i0;   // idx output region read back as fp32
  }
}

// ---------------------------------------------------------------------------
// Epilogue: block = (b, 64-hw tile). Stage the 64 gathered w-rows into LDS
// (wt[c][r], stride 65 -> 2-way banks, free), then fully-coalesced vf4
// global reads/writes for q and ste = fl(fl(q - x) + x).
// ---------------------------------------------------------------------------
#define WT_S 65

__global__ void k_epilogue(const float* __restrict__ x, const float* __restrict__ w,
                           const float* __restrict__ oidx, float* __restrict__ out) {
#pragma clang fp contract(off)
  __shared__ int   idxs[MT];
  __shared__ float wt[CODE_DIM * WT_S];   // wt[c][r], 66560 B

  const int t   = threadIdx.x;
  const int n0  = blockIdx.x * MT;
  const int b   = n0 >> 10;
  const int hw0 = n0 & 1023;

  if (t < MT) idxs[t] = (int)oidx[n0 + t];
  __syncthreads();

  // stage wt: jobs j -> (r = j&63, cq = j>>6); lanes span r -> per-lane 16-B
  // gathers from 64 w-rows (L1/L2 absorb; each row consumed fully by the
  // 4 sibling threads), LDS writes bank=(c+r)%32 with r spanning -> free.
#pragma unroll
  for (int i = 0; i < 16; ++i) {
    const int j  = t + 256 * i;
    const int r  = j & 63;
    const int cq = j >> 6;     // 0..63
    vf4 v = *(const vf4*)(w + (size_t)idxs[r] * CODE_DIM + cq * 4);
    wt[(cq * 4 + 0) * WT_S + r] = v.x;
    wt[(cq * 4 + 1) * WT_S + r] = v.y;
    wt[(cq * 4 + 2) * WT_S + r] = v.z;
    wt[(cq * 4 + 3) * WT_S + r] = v.w;
  }
  __syncthreads();

  // outputs: jobs j -> (c = j>>4, rq = j&15); global vf4 fully coalesced
#pragma unroll
  for (int i = 0; i < 16; ++i) {
    const int j  = t + 256 * i;
    const int c  = j >> 4;     // 0..255
    const int rq = j & 15;
    const size_t off = (size_t)(b * CODE_DIM + c) * HWSZ + hw0 + rq * 4;
    vf4 xv = *(const vf4*)(x + off);
    vf4 q, s;
#pragma unroll
    for (int u = 0; u < 4; ++u) {
      const float qv = wt[c * WT_S + rq * 4 + u];
      q[u] = qv;
      const float d = qv - xv[u];
      s[u] = d + xv[u];
    }
    *(vf4*)(out + off) = q;
    *(vf4*)(out + (size_t)QELEMS + off) = s;
  }
}

extern "C" void kernel_launch(void* const* d_in, const int* in_sizes, int n_in,
                              void* d_out, int out_size, void* d_ws, size_t ws_size,
                              hipStream_t stream) {
  const float* x = (const float*)d_in[0];   // (64,256,32,32) fp32
  const float* w = (const float*)d_in[1];   // (1024,256) fp32
  float* out  = (float*)d_out;
  float* oidx = out + 2 * (size_t)QELEMS;          // idx region (written as float)
  // scratch for sx/sw lives inside the ste region; epilogue (which runs after
  // k_argmin completes, stream-ordered) overwrites it later
  float* sx = out + (size_t)QELEMS;                // 65536 floats
  float* sw = out + (size_t)QELEMS + NROWS;        // 1024 floats

  k_sumsq_w<<<CODE_SIZE / 256, 256, 0, stream>>>(w, sw);
  k_sumsq_x<<<NROWS / 256, 256, 0, stream>>>(x, sx);
  k_argmin<<<NROWS / MT, 256, 0, stream>>>(x, w, sx, sw, oidx);
  k_epilogue<<<NROWS / MT, 256, 0, stream>>>(x, w, oidx, out);
}